// Round 2
// baseline (962.894 us; speedup 1.0000x reference)
//
#include <hip/hip_runtime.h>
#include <hip/hip_bf16.h>

#define NRAYS 4096
#define NS 256
#define G 160
#define G2 (160*160)
#define G3 (160*160*160)
#define K0DIM 12
#define WIDTH 128
#define CHUNK 32
#define NCHUNK 8
#define HSTR 36              // CHUNK+4 pad: rows 144 B -> 16B-aligned, bank-skewed
#define ACT_SHIFT_F (-4.5951198501345889f)
#define TNEAR 0.2f
#define TFAR 1.8f

typedef unsigned short u16;
typedef unsigned int u32;

__device__ __forceinline__ float bf2f(u16 u) {
    union { u32 i; float f; } v; v.i = ((u32)u) << 16; return v.f;
}
__device__ __forceinline__ u16 f2bf(float f) {   // RTNE fp32 -> bf16
    union { float f; u32 u; } v; v.f = f;
    u32 r = v.u + 0x7FFFu + ((v.u >> 16) & 1u);
    return (u16)(r >> 16);
}

// dtype-polymorphic scalar load
__device__ __forceinline__ float loadv(const float* p, int i) { return p[i]; }
__device__ __forceinline__ float loadv(const u16* p, int i)   { return bf2f(p[i]); }
// dtype-polymorphic store
__device__ __forceinline__ void storev(float* p, int i, float v) { p[i] = v; }
__device__ __forceinline__ void storev(u16* p, int i, float v)   { p[i] = f2bf(v); }

struct Coords { int idx; float fx, fy, fz; };

__device__ __forceinline__ Coords coords_for(float px, float py, float pz) {
    float gx = fminf(fmaxf((px + 1.0f) * 79.5f, 0.0f), 159.0f);
    float gy = fminf(fmaxf((py + 1.0f) * 79.5f, 0.0f), 159.0f);
    float gz = fminf(fmaxf((pz + 1.0f) * 79.5f, 0.0f), 159.0f);
    int ix = (int)gx; if (ix > 158) ix = 158;
    int iy = (int)gy; if (iy > 158) iy = 158;
    int iz = (int)gz; if (iz > 158) iz = 158;
    Coords c;
    c.idx = (ix * G + iy) * G + iz;
    c.fx = gx - (float)ix; c.fy = gy - (float)iy; c.fz = gz - (float)iz;
    return c;
}

template <typename T>
__device__ __forceinline__ float trilerp(const T* __restrict__ g, Coords c) {
    float c000 = loadv(g, c.idx);
    float c001 = loadv(g, c.idx + 1);
    float c010 = loadv(g, c.idx + G);
    float c011 = loadv(g, c.idx + G + 1);
    float c100 = loadv(g, c.idx + G2);
    float c101 = loadv(g, c.idx + G2 + 1);
    float c110 = loadv(g, c.idx + G2 + G);
    float c111 = loadv(g, c.idx + G2 + G + 1);
    float c00 = c000 * (1.0f - c.fz) + c001 * c.fz;
    float c01 = c010 * (1.0f - c.fz) + c011 * c.fz;
    float c10 = c100 * (1.0f - c.fz) + c101 * c.fz;
    float c11 = c110 * (1.0f - c.fz) + c111 * c.fz;
    float c0 = c00 * (1.0f - c.fy) + c01 * c.fy;
    float c1 = c10 * (1.0f - c.fy) + c11 * c.fy;
    return c0 * (1.0f - c.fx) + c1 * c.fx;
}

// 4x4 register-tile FMA: wv = 4 bf16 weights (over j), xv = 4 fp32 x (over s)
#define FMA16(wv, xv)                                                          \
    { float w_;                                                                \
      w_ = bf2f((wv).x); a0.x += w_*(xv).x; a0.y += w_*(xv).y;                 \
                         a0.z += w_*(xv).z; a0.w += w_*(xv).w;                 \
      w_ = bf2f((wv).y); a1.x += w_*(xv).x; a1.y += w_*(xv).y;                 \
                         a1.z += w_*(xv).z; a1.w += w_*(xv).w;                 \
      w_ = bf2f((wv).z); a2.x += w_*(xv).x; a2.y += w_*(xv).y;                 \
                         a2.z += w_*(xv).z; a2.w += w_*(xv).w;                 \
      w_ = bf2f((wv).w); a3.x += w_*(xv).x; a3.y += w_*(xv).y;                 \
                         a3.z += w_*(xv).z; a3.w += w_*(xv).w; }

// mode: 0 = buffers hold bf16, 1 = buffers hold fp32
__global__ void decide_mode(const u16* __restrict__ rays_d_u16, int* __restrict__ mode) {
    if (blockIdx.x == 0 && threadIdx.x == 0) {
        int bad = 0;
        for (int i = 0; i < 128; i++) {
            u16 u = rays_d_u16[i];
            int e = (u >> 7) & 0xFF;
            int m = u & 0x7F;
            float v = bf2f(u);
            if (e == 0xFF || (e == 0 && m != 0) || fabsf(v) > 32.0f) bad++;
        }
        *mode = (bad >= 4) ? 1 : 0;
    }
}

template <typename T, typename OT, int MODE>
__global__ __launch_bounds__(256)
void dvgo_fused(const T* __restrict__ rays_o, const T* __restrict__ rays_d,
                const T* __restrict__ density, const T* __restrict__ k0,
                const T* __restrict__ W0, const T* __restrict__ b0,
                const T* __restrict__ W1, const T* __restrict__ b1,
                const T* __restrict__ W2, const T* __restrict__ b2,
                OT* __restrict__ out, const int* __restrict__ mode)
{
    if (*mode != MODE) return;   // uniform early-exit for the wrong-dtype instantiation

    __shared__ __align__(16) u16   W1h[WIDTH * WIDTH];     // 32768 B (bf16 weights)
    __shared__ __align__(16) float hT[WIDTH * HSTR];       // 18432 B
    __shared__ __align__(16) float W0hf[K0DIM * WIDTH];    // 6144 B (fp32)
    __shared__ __align__(16) float featT[K0DIM * HSTR];    // 1728 B
    __shared__ __align__(16) float W2Tf[3 * WIDTH];        // 1536 B (fp32)
    __shared__ float base0[WIDTH];
    __shared__ float b1s[WIDTH];
    __shared__ float b2s[3];
    __shared__ float vembs[27];
    __shared__ float wts[NS];
    __shared__ float red[96];
    __shared__ float ainvs;

    const int r = blockIdx.x;
    const int tid = threadIdx.x;

    const float o0 = loadv(rays_o, r*3+0);
    const float o1 = loadv(rays_o, r*3+1);
    const float o2 = loadv(rays_o, r*3+2);
    const float d0 = loadv(rays_d, r*3+0);
    const float d1 = loadv(rays_d, r*3+1);
    const float d2 = loadv(rays_d, r*3+2);

    // ---- stage weights into LDS ----
    if (MODE == 0) {
        // bf16 source: straight copy of W1 (8 u16 per uint4)
        const uint4* src = (const uint4*)W1;
        uint4* dst = (uint4*)W1h;
        #pragma unroll
        for (int k = tid; k < WIDTH*WIDTH/8; k += 256) dst[k] = src[k];
        for (int k = tid; k < K0DIM*WIDTH; k += 256) W0hf[k] = loadv(W0, k);
    } else {
        // fp32 source: round W1 to bf16 for LDS; W0 stays fp32
        const float4* src = (const float4*)W1;
        #pragma unroll
        for (int k = tid; k < WIDTH*WIDTH/4; k += 256) {
            float4 w = src[k];
            ushort4 h;
            h.x = f2bf(w.x); h.y = f2bf(w.y); h.z = f2bf(w.z); h.w = f2bf(w.w);
            *(ushort4*)&W1h[k*4] = h;
        }
        const float4* s0p = (const float4*)W0;
        float4* d0p = (float4*)W0hf;
        for (int k = tid; k < K0DIM*WIDTH/4; k += 256) d0p[k] = s0p[k];
    }
    for (int k = tid; k < 3*WIDTH; k += 256) {
        int c = k >> 7, i = k & 127;
        W2Tf[k] = loadv(W2, i*3 + c);
    }
    if (tid < WIDTH) b1s[tid] = loadv(b1, tid);
    if (tid < 3)     b2s[tid] = loadv(b2, tid);

    // ---- view embedding (per-ray constant) ----
    if (tid < 27) {
        float inv = rsqrtf(d0*d0 + d1*d1 + d2*d2);
        float v0 = d0*inv, v1 = d1*inv, v2 = d2*inv;
        float val;
        if (tid < 3) {
            val = (tid == 0) ? v0 : ((tid == 1) ? v1 : v2);
        } else if (tid < 15) {
            int t2 = tid - 3; int dd = t2 >> 2; int p = t2 & 3;
            float vd = (dd == 0) ? v0 : ((dd == 1) ? v1 : v2);
            val = sinf(vd * (float)(1 << p));
        } else {
            int t2 = tid - 15; int dd = t2 >> 2; int p = t2 & 3;
            float vd = (dd == 0) ? v0 : ((dd == 1) ? v1 : v2);
            val = cosf(vd * (float)(1 << p));
        }
        vembs[tid] = val;
    }
    __syncthreads();

    // ---- base0 = b0 + vemb @ W0[12:39]  (per-ray) ----
    if (tid < WIDTH) {
        float a = loadv(b0, tid);
        #pragma unroll
        for (int i = 0; i < 27; i++)
            a += vembs[i] * loadv(W0, (K0DIM + i)*WIDTH + tid);
        base0[tid] = a;
    }

    // ---- alpha for my sample ----
    {
        int s = tid;
        float tv = TNEAR + (TFAR - TNEAR) * ((float)s * (1.0f/(float)(NS-1)));
        Coords c = coords_for(o0 + d0*tv, o1 + d1*tv, o2 + d2*tv);
        float sigma = trilerp(density, c);
        float alpha = 1.0f - rsqrtf(1.0f + __expf(sigma + ACT_SHIFT_F));
        wts[s] = alpha;
    }
    __syncthreads();

    // ---- serial transmittance scan (alpha -> weights in place) ----
    if (tid == 0) {
        float w = 1.0f;
        for (int s = 0; s < NS; s++) {
            float a = wts[s];
            wts[s] = a * w;
            w *= (1.0f - a + 1e-10f);
        }
        ainvs = w;
    }
    __syncthreads();

    // ---- MLP over sample chunks ----
    const int jt = tid & 31;
    const int st = tid >> 5;      // 0..7
    const int j0 = jt * 4;
    const int s0 = st * 4;
    const int l2c = tid >> 5;     // layer2: channel for tid<96
    const int l2s = tid & 31;

    float rgbacc = 0.0f;

    for (int cc = 0; cc < NCHUNK; cc++) {
        const int c0 = cc * CHUNK;

        // feat trilerp: 12 ch x 32 samples
        for (int task = tid; task < K0DIM*CHUNK; task += 256) {
            int ch = task >> 5;
            int sl = task & 31;
            int s = c0 + sl;
            float tv = TNEAR + (TFAR - TNEAR) * ((float)s * (1.0f/(float)(NS-1)));
            Coords c = coords_for(o0 + d0*tv, o1 + d1*tv, o2 + d2*tv);
            featT[ch*HSTR + sl] = trilerp(k0 + (size_t)ch*G3, c);
        }
        __syncthreads();

        // layer 0: h0 = relu(base0 + feat @ W0[0:12])
        float4 a0, a1, a2, a3;
        {
            float v;
            v = base0[j0+0]; a0 = make_float4(v,v,v,v);
            v = base0[j0+1]; a1 = make_float4(v,v,v,v);
            v = base0[j0+2]; a2 = make_float4(v,v,v,v);
            v = base0[j0+3]; a3 = make_float4(v,v,v,v);
        }
        #pragma unroll
        for (int i = 0; i < K0DIM; i++) {
            float4 xv = *(const float4*)&featT[i*HSTR + s0];
            float4 wv = *(const float4*)&W0hf[i*WIDTH + j0];
            a0.x += wv.x*xv.x; a0.y += wv.x*xv.y; a0.z += wv.x*xv.z; a0.w += wv.x*xv.w;
            a1.x += wv.y*xv.x; a1.y += wv.y*xv.y; a1.z += wv.y*xv.z; a1.w += wv.y*xv.w;
            a2.x += wv.z*xv.x; a2.y += wv.z*xv.y; a2.z += wv.z*xv.z; a2.w += wv.z*xv.w;
            a3.x += wv.w*xv.x; a3.y += wv.w*xv.y; a3.z += wv.w*xv.z; a3.w += wv.w*xv.w;
        }
        a0.x = fmaxf(a0.x, 0.0f); a0.y = fmaxf(a0.y, 0.0f); a0.z = fmaxf(a0.z, 0.0f); a0.w = fmaxf(a0.w, 0.0f);
        a1.x = fmaxf(a1.x, 0.0f); a1.y = fmaxf(a1.y, 0.0f); a1.z = fmaxf(a1.z, 0.0f); a1.w = fmaxf(a1.w, 0.0f);
        a2.x = fmaxf(a2.x, 0.0f); a2.y = fmaxf(a2.y, 0.0f); a2.z = fmaxf(a2.z, 0.0f); a2.w = fmaxf(a2.w, 0.0f);
        a3.x = fmaxf(a3.x, 0.0f); a3.y = fmaxf(a3.y, 0.0f); a3.z = fmaxf(a3.z, 0.0f); a3.w = fmaxf(a3.w, 0.0f);
        *(float4*)&hT[(j0+0)*HSTR + s0] = a0;
        *(float4*)&hT[(j0+1)*HSTR + s0] = a1;
        *(float4*)&hT[(j0+2)*HSTR + s0] = a2;
        *(float4*)&hT[(j0+3)*HSTR + s0] = a3;
        __syncthreads();

        // layer 1: h1 = relu(h0 @ W1 + b1)
        {
            float v;
            v = b1s[j0+0]; a0 = make_float4(v,v,v,v);
            v = b1s[j0+1]; a1 = make_float4(v,v,v,v);
            v = b1s[j0+2]; a2 = make_float4(v,v,v,v);
            v = b1s[j0+3]; a3 = make_float4(v,v,v,v);
        }
        #pragma unroll 8
        for (int i = 0; i < WIDTH; i++) {
            float4 xv = *(const float4*)&hT[i*HSTR + s0];
            ushort4 wv = *(const ushort4*)&W1h[i*WIDTH + j0];
            FMA16(wv, xv);
        }
        __syncthreads();   // all hT reads done before overwrite
        a0.x = fmaxf(a0.x, 0.0f); a0.y = fmaxf(a0.y, 0.0f); a0.z = fmaxf(a0.z, 0.0f); a0.w = fmaxf(a0.w, 0.0f);
        a1.x = fmaxf(a1.x, 0.0f); a1.y = fmaxf(a1.y, 0.0f); a1.z = fmaxf(a1.z, 0.0f); a1.w = fmaxf(a1.w, 0.0f);
        a2.x = fmaxf(a2.x, 0.0f); a2.y = fmaxf(a2.y, 0.0f); a2.z = fmaxf(a2.z, 0.0f); a2.w = fmaxf(a2.w, 0.0f);
        a3.x = fmaxf(a3.x, 0.0f); a3.y = fmaxf(a3.y, 0.0f); a3.z = fmaxf(a3.z, 0.0f); a3.w = fmaxf(a3.w, 0.0f);
        *(float4*)&hT[(j0+0)*HSTR + s0] = a0;
        *(float4*)&hT[(j0+1)*HSTR + s0] = a1;
        *(float4*)&hT[(j0+2)*HSTR + s0] = a2;
        *(float4*)&hT[(j0+3)*HSTR + s0] = a3;
        __syncthreads();

        // layer 2: rgb = sigmoid(h1 @ W2 + b2); weighted accumulate
        if (tid < 96) {
            float acc = b2s[l2c];
            #pragma unroll 8
            for (int i = 0; i < WIDTH; i++)
                acc += hT[i*HSTR + l2s] * W2Tf[l2c*WIDTH + i];
            float rgb = 1.0f / (1.0f + __expf(-acc));
            rgbacc += wts[c0 + l2s] * rgb;
        }
        __syncthreads();
    }

    if (tid < 96) red[tid] = rgbacc;
    __syncthreads();
    if (tid < 3) {
        float s = 0.0f;
        #pragma unroll
        for (int k = 0; k < 32; k++) s += red[tid*32 + k];
        storev(out, r*3 + tid, s + ainvs);
    }
}

extern "C" void kernel_launch(void* const* d_in, const int* in_sizes, int n_in,
                              void* d_out, int out_size, void* d_ws, size_t ws_size,
                              hipStream_t stream) {
    int* mode = (int*)d_ws;
    decide_mode<<<dim3(1), dim3(64), 0, stream>>>((const u16*)d_in[1], mode);

    // bf16 interpretation
    dvgo_fused<u16, u16, 0><<<dim3(NRAYS), dim3(256), 0, stream>>>(
        (const u16*)d_in[0], (const u16*)d_in[1], (const u16*)d_in[2],
        (const u16*)d_in[3], (const u16*)d_in[4], (const u16*)d_in[5],
        (const u16*)d_in[6], (const u16*)d_in[7], (const u16*)d_in[8],
        (const u16*)d_in[9], (u16*)d_out, mode);

    // fp32 interpretation
    dvgo_fused<float, float, 1><<<dim3(NRAYS), dim3(256), 0, stream>>>(
        (const float*)d_in[0], (const float*)d_in[1], (const float*)d_in[2],
        (const float*)d_in[3], (const float*)d_in[4], (const float*)d_in[5],
        (const float*)d_in[6], (const float*)d_in[7], (const float*)d_in[8],
        (const float*)d_in[9], (float*)d_out, mode);
}

// Round 3
// 644.089 us; speedup vs baseline: 1.4950x; 1.4950x over previous
//
#include <hip/hip_runtime.h>
#include <hip/hip_bf16.h>

#define NRAYS 4096
#define NS 256
#define G 160
#define G2 (160*160)
#define G3 (160*160*160)
#define K0DIM 12
#define WIDTH 128
#define CHUNK 32
#define NCHUNK 8
#define HSTR 36              // featT pad: rows 144 B
#define HBS 136              // bf16 row stride for h0B/h1B/W1T: 272 B = 68 dwords -> 4-bank skew
#define ACT_SHIFT_F (-4.5951198501345889f)
#define TNEAR 0.2f
#define TFAR 1.8f

typedef unsigned short u16;
typedef unsigned int u32;
typedef __attribute__((ext_vector_type(8))) short short8;   // 8 bf16 = 4 VGPRs (MFMA A/B frag)
typedef __attribute__((ext_vector_type(4))) float floatx4;  // MFMA C/D frag

__device__ __forceinline__ float bf2f(u16 u) {
    union { u32 i; float f; } v; v.i = ((u32)u) << 16; return v.f;
}
__device__ __forceinline__ u16 f2bf(float f) {   // RTNE fp32 -> bf16
    union { float f; u32 u; } v; v.f = f;
    u32 r = v.u + 0x7FFFu + ((v.u >> 16) & 1u);
    return (u16)(r >> 16);
}

// dtype-polymorphic scalar load/store
__device__ __forceinline__ float loadv(const float* p, int i) { return p[i]; }
__device__ __forceinline__ float loadv(const u16* p, int i)   { return bf2f(p[i]); }
__device__ __forceinline__ void storev(float* p, int i, float v) { p[i] = v; }
__device__ __forceinline__ void storev(u16* p, int i, float v)   { p[i] = f2bf(v); }

struct Coords { int idx; float fx, fy, fz; };

__device__ __forceinline__ Coords coords_for(float px, float py, float pz) {
    float gx = fminf(fmaxf((px + 1.0f) * 79.5f, 0.0f), 159.0f);
    float gy = fminf(fmaxf((py + 1.0f) * 79.5f, 0.0f), 159.0f);
    float gz = fminf(fmaxf((pz + 1.0f) * 79.5f, 0.0f), 159.0f);
    int ix = (int)gx; if (ix > 158) ix = 158;
    int iy = (int)gy; if (iy > 158) iy = 158;
    int iz = (int)gz; if (iz > 158) iz = 158;
    Coords c;
    c.idx = (ix * G + iy) * G + iz;
    c.fx = gx - (float)ix; c.fy = gy - (float)iy; c.fz = gz - (float)iz;
    return c;
}

template <typename T>
__device__ __forceinline__ float trilerp(const T* __restrict__ g, Coords c) {
    float c000 = loadv(g, c.idx);
    float c001 = loadv(g, c.idx + 1);
    float c010 = loadv(g, c.idx + G);
    float c011 = loadv(g, c.idx + G + 1);
    float c100 = loadv(g, c.idx + G2);
    float c101 = loadv(g, c.idx + G2 + 1);
    float c110 = loadv(g, c.idx + G2 + G);
    float c111 = loadv(g, c.idx + G2 + G + 1);
    float c00 = c000 * (1.0f - c.fz) + c001 * c.fz;
    float c01 = c010 * (1.0f - c.fz) + c011 * c.fz;
    float c10 = c100 * (1.0f - c.fz) + c101 * c.fz;
    float c11 = c110 * (1.0f - c.fz) + c111 * c.fz;
    float c0 = c00 * (1.0f - c.fy) + c01 * c.fy;
    float c1 = c10 * (1.0f - c.fy) + c11 * c.fy;
    return c0 * (1.0f - c.fx) + c1 * c.fx;
}

// mode: 0 = buffers hold bf16, 1 = buffers hold fp32
__global__ void decide_mode(const u16* __restrict__ rays_d_u16, int* __restrict__ mode) {
    if (blockIdx.x == 0 && threadIdx.x == 0) {
        int bad = 0;
        for (int i = 0; i < 128; i++) {
            u16 u = rays_d_u16[i];
            int e = (u >> 7) & 0xFF;
            int m = u & 0x7F;
            float v = bf2f(u);
            if (e == 0xFF || (e == 0 && m != 0) || fabsf(v) > 32.0f) bad++;
        }
        *mode = (bad >= 4) ? 1 : 0;
    }
}

template <typename T, typename OT, int MODE>
__global__ __launch_bounds__(256)
void dvgo_fused(const T* __restrict__ rays_o, const T* __restrict__ rays_d,
                const T* __restrict__ density, const T* __restrict__ k0,
                const T* __restrict__ W0, const T* __restrict__ b0,
                const T* __restrict__ W1, const T* __restrict__ b1,
                const T* __restrict__ W2, const T* __restrict__ b2,
                OT* __restrict__ out, const int* __restrict__ mode)
{
    if (*mode != MODE) return;   // uniform early-exit for the wrong-dtype instantiation

    __shared__ __align__(16) u16   W1T[WIDTH * HBS];       // 34816 B  W1T[n][k] = W1[k][n], bf16
    __shared__ __align__(16) u16   h0B[CHUNK * HBS];       // 8704 B   h0 bf16 [sample][k]
    __shared__ __align__(16) u16   h1B[CHUNK * HBS];       // 8704 B   h1 bf16 [sample][j]
    __shared__ __align__(16) u16   W0h[K0DIM * WIDTH];     // 3072 B   bf16
    __shared__ __align__(16) float featT[K0DIM * HSTR];    // 1728 B
    __shared__ __align__(16) float W2Tf[3 * WIDTH];        // 1536 B
    __shared__ float base0[WIDTH];
    __shared__ float b1s[WIDTH];
    __shared__ float b2s[3];
    __shared__ float vembs[27];
    __shared__ float wts[NS];
    __shared__ float red[96];
    __shared__ float ainvs;

    const int r = blockIdx.x;
    const int tid = threadIdx.x;

    const float o0 = loadv(rays_o, r*3+0);
    const float o1 = loadv(rays_o, r*3+1);
    const float o2 = loadv(rays_o, r*3+2);
    const float d0 = loadv(rays_d, r*3+0);
    const float d1 = loadv(rays_d, r*3+1);
    const float d2 = loadv(rays_d, r*3+2);

    // ---- stage weights into LDS (coalesced global reads, scattered LDS writes) ----
    for (int idx = tid; idx < WIDTH*WIDTH; idx += 256) {
        int k = idx >> 7, n = idx & 127;
        W1T[n*HBS + k] = f2bf(loadv(W1, idx));   // transpose: W1T[n][k]
    }
    for (int k = tid; k < K0DIM*WIDTH; k += 256) W0h[k] = f2bf(loadv(W0, k));
    for (int k = tid; k < 3*WIDTH; k += 256) {
        int c = k >> 7, i = k & 127;
        W2Tf[k] = loadv(W2, i*3 + c);
    }
    if (tid < WIDTH) b1s[tid] = loadv(b1, tid);
    if (tid < 3)     b2s[tid] = loadv(b2, tid);

    // ---- view embedding (per-ray constant) ----
    if (tid < 27) {
        float inv = rsqrtf(d0*d0 + d1*d1 + d2*d2);
        float v0 = d0*inv, v1 = d1*inv, v2 = d2*inv;
        float val;
        if (tid < 3) {
            val = (tid == 0) ? v0 : ((tid == 1) ? v1 : v2);
        } else if (tid < 15) {
            int t2 = tid - 3; int dd = t2 >> 2; int p = t2 & 3;
            float vd = (dd == 0) ? v0 : ((dd == 1) ? v1 : v2);
            val = sinf(vd * (float)(1 << p));
        } else {
            int t2 = tid - 15; int dd = t2 >> 2; int p = t2 & 3;
            float vd = (dd == 0) ? v0 : ((dd == 1) ? v1 : v2);
            val = cosf(vd * (float)(1 << p));
        }
        vembs[tid] = val;
    }
    __syncthreads();

    // ---- base0 = b0 + vemb @ W0[12:39]  (per-ray) ----
    if (tid < WIDTH) {
        float a = loadv(b0, tid);
        #pragma unroll
        for (int i = 0; i < 27; i++)
            a += vembs[i] * loadv(W0, (K0DIM + i)*WIDTH + tid);
        base0[tid] = a;
    }

    // ---- alpha for my sample ----
    {
        int s = tid;
        float tv = TNEAR + (TFAR - TNEAR) * ((float)s * (1.0f/(float)(NS-1)));
        Coords c = coords_for(o0 + d0*tv, o1 + d1*tv, o2 + d2*tv);
        float sigma = trilerp(density, c);
        float alpha = 1.0f - rsqrtf(1.0f + __expf(sigma + ACT_SHIFT_F));
        wts[s] = alpha;
    }
    __syncthreads();

    // ---- serial transmittance scan (alpha -> weights in place) ----
    if (tid == 0) {
        float w = 1.0f;
        for (int s = 0; s < NS; s++) {
            float a = wts[s];
            wts[s] = a * w;
            w *= (1.0f - a + 1e-10f);
        }
        ainvs = w;
    }
    __syncthreads();

    // ---- per-thread role constants ----
    const int jt = tid & 31;      // L0: output group
    const int st = tid >> 5;      // L0: sample group 0..7
    const int j0 = jt * 4;
    const int s0 = st * 4;
    const int l2c = tid >> 5;     // L2: channel for tid<96
    const int l2s = tid & 31;

    const int wvid = tid >> 6;    // wave 0..3
    const int lane = tid & 63;
    const int mt   = wvid & 1;            // sample tile (16 rows)
    const int nh   = wvid >> 1;           // output half (64 cols)
    const int arow = mt*16 + (lane & 15); // A/M row for this lane
    const int kcol = (lane >> 4) * 8;     // k offset within 32-wide K step
    const int ncol = lane & 15;           // B/N col for this lane
    const int drow0 = mt*16 + (lane >> 4) * 4;  // first D row for this lane

    float rgbacc = 0.0f;

    for (int cc = 0; cc < NCHUNK; cc++) {
        const int c0 = cc * CHUNK;

        // (a) feat trilerp: 12 ch x 32 samples
        for (int task = tid; task < K0DIM*CHUNK; task += 256) {
            int ch = task >> 5;
            int sl = task & 31;
            int s = c0 + sl;
            float tv = TNEAR + (TFAR - TNEAR) * ((float)s * (1.0f/(float)(NS-1)));
            Coords c = coords_for(o0 + d0*tv, o1 + d1*tv, o2 + d2*tv);
            featT[ch*HSTR + sl] = trilerp(k0 + (size_t)ch*G3, c);
        }
        __syncthreads();   // A

        // (b) layer 0: h0 = relu(base0 + feat @ W0[0:12]) -> bf16 LDS [sample][k]
        {
            float acc[4][4];   // [r over j][si over s]
            #pragma unroll
            for (int rr = 0; rr < 4; rr++) {
                float v = base0[j0+rr];
                acc[rr][0] = v; acc[rr][1] = v; acc[rr][2] = v; acc[rr][3] = v;
            }
            #pragma unroll
            for (int i = 0; i < K0DIM; i++) {
                float4 xv = *(const float4*)&featT[i*HSTR + s0];
                ushort4 wv = *(const ushort4*)&W0h[i*WIDTH + j0];
                float w;
                w = bf2f(wv.x); acc[0][0]+=w*xv.x; acc[0][1]+=w*xv.y; acc[0][2]+=w*xv.z; acc[0][3]+=w*xv.w;
                w = bf2f(wv.y); acc[1][0]+=w*xv.x; acc[1][1]+=w*xv.y; acc[1][2]+=w*xv.z; acc[1][3]+=w*xv.w;
                w = bf2f(wv.z); acc[2][0]+=w*xv.x; acc[2][1]+=w*xv.y; acc[2][2]+=w*xv.z; acc[2][3]+=w*xv.w;
                w = bf2f(wv.w); acc[3][0]+=w*xv.x; acc[3][1]+=w*xv.y; acc[3][2]+=w*xv.z; acc[3][3]+=w*xv.w;
            }
            #pragma unroll
            for (int si = 0; si < 4; si++) {
                ushort4 h;
                h.x = f2bf(fmaxf(acc[0][si], 0.0f));
                h.y = f2bf(fmaxf(acc[1][si], 0.0f));
                h.z = f2bf(fmaxf(acc[2][si], 0.0f));
                h.w = f2bf(fmaxf(acc[3][si], 0.0f));
                *(ushort4*)&h0B[(s0+si)*HBS + j0] = h;
            }
        }
        __syncthreads();   // B

        // (c) layer 1 via MFMA: h1[32][128] = relu(h0[32][128] @ W1[128][128] + b1)
        {
            floatx4 acc[4];
            #pragma unroll
            for (int t = 0; t < 4; t++) {
                float bj = b1s[nh*64 + t*16 + ncol];
                acc[t] = (floatx4){bj, bj, bj, bj};
            }
            #pragma unroll
            for (int kq = 0; kq < 4; kq++) {
                short8 af = *(const short8*)&h0B[arow*HBS + kq*32 + kcol];
                #pragma unroll
                for (int t = 0; t < 4; t++) {
                    short8 bf = *(const short8*)&W1T[(nh*64 + t*16 + ncol)*HBS + kq*32 + kcol];
                    acc[t] = __builtin_amdgcn_mfma_f32_16x16x32_bf16(af, bf, acc[t], 0, 0, 0);
                }
            }
            // epilogue: ReLU -> bf16 -> h1B[sample][j]
            #pragma unroll
            for (int t = 0; t < 4; t++) {
                int j = nh*64 + t*16 + ncol;
                #pragma unroll
                for (int rI = 0; rI < 4; rI++) {
                    h1B[(drow0 + rI)*HBS + j] = f2bf(fmaxf(acc[t][rI], 0.0f));
                }
            }
        }
        __syncthreads();   // C

        // (d) layer 2: rgb = sigmoid(h1 @ W2 + b2); weighted accumulate
        if (tid < 96) {
            float acc2 = b2s[l2c];
            const u16* hrow = &h1B[l2s*HBS];
            const float* wrow = &W2Tf[l2c*WIDTH];
            #pragma unroll
            for (int i = 0; i < WIDTH; i += 8) {
                ushort4 p0 = *(const ushort4*)&hrow[i];
                ushort4 p1 = *(const ushort4*)&hrow[i+4];
                acc2 += bf2f(p0.x)*wrow[i+0] + bf2f(p0.y)*wrow[i+1]
                      + bf2f(p0.z)*wrow[i+2] + bf2f(p0.w)*wrow[i+3]
                      + bf2f(p1.x)*wrow[i+4] + bf2f(p1.y)*wrow[i+5]
                      + bf2f(p1.z)*wrow[i+6] + bf2f(p1.w)*wrow[i+7];
            }
            float rgb = 1.0f / (1.0f + __expf(-acc2));
            rgbacc += wts[c0 + l2s] * rgb;
        }
        __syncthreads();   // D
    }

    if (tid < 96) red[tid] = rgbacc;
    __syncthreads();
    if (tid < 3) {
        float s = 0.0f;
        #pragma unroll
        for (int k = 0; k < 32; k++) s += red[tid*32 + k];
        storev(out, r*3 + tid, s + ainvs);
    }
}

extern "C" void kernel_launch(void* const* d_in, const int* in_sizes, int n_in,
                              void* d_out, int out_size, void* d_ws, size_t ws_size,
                              hipStream_t stream) {
    int* mode = (int*)d_ws;
    decide_mode<<<dim3(1), dim3(64), 0, stream>>>((const u16*)d_in[1], mode);

    // bf16 interpretation
    dvgo_fused<u16, u16, 0><<<dim3(NRAYS), dim3(256), 0, stream>>>(
        (const u16*)d_in[0], (const u16*)d_in[1], (const u16*)d_in[2],
        (const u16*)d_in[3], (const u16*)d_in[4], (const u16*)d_in[5],
        (const u16*)d_in[6], (const u16*)d_in[7], (const u16*)d_in[8],
        (const u16*)d_in[9], (u16*)d_out, mode);

    // fp32 interpretation
    dvgo_fused<float, float, 1><<<dim3(NRAYS), dim3(256), 0, stream>>>(
        (const float*)d_in[0], (const float*)d_in[1], (const float*)d_in[2],
        (const float*)d_in[3], (const float*)d_in[4], (const float*)d_in[5],
        (const float*)d_in[6], (const float*)d_in[7], (const float*)d_in[8],
        (const float*)d_in[9], (float*)d_out, mode);
}

// Round 4
// 545.419 us; speedup vs baseline: 1.7654x; 1.1809x over previous
//
#include <hip/hip_runtime.h>
#include <hip/hip_bf16.h>

#define NRAYS 4096
#define NS 256
#define G 160
#define G2 (160*160)
#define G3 (160*160*160)
#define K0DIM 12
#define WIDTH 128
#define CHUNK 32
#define NCHUNK 8
#define HSTR 36              // featT pad: rows 144 B
#define HBS 136              // h0B bf16 row stride (272 B = 17*16 -> aligned, 2-way banks = free)
#define ACT_SHIFT_F (-4.5951198501345889f)
#define TNEAR 0.2f
#define TFAR 1.8f

typedef unsigned short u16;
typedef unsigned int u32;
typedef __attribute__((ext_vector_type(8))) short short8;   // 8 bf16 = 4 VGPRs (MFMA A/B frag)
typedef __attribute__((ext_vector_type(4))) float floatx4;  // MFMA C/D frag

// W1f[kq][qsub][col][j]: B-frag for (kq, quarter qsub, output col) = 16 contiguous bytes
#define W1F_IDX(kq, qs, n) (((((kq)<<2) + (qs)) * 128 + (n)) << 3)

__device__ __forceinline__ float bf2f(u16 u) {
    union { u32 i; float f; } v; v.i = ((u32)u) << 16; return v.f;
}
__device__ __forceinline__ u16 f2bf(float f) {   // RTNE fp32 -> bf16
    union { float f; u32 u; } v; v.f = f;
    u32 r = v.u + 0x7FFFu + ((v.u >> 16) & 1u);
    return (u16)(r >> 16);
}

__device__ __forceinline__ float loadv(const float* p, int i) { return p[i]; }
__device__ __forceinline__ float loadv(const u16* p, int i)   { return bf2f(p[i]); }
__device__ __forceinline__ void storev(float* p, int i, float v) { p[i] = v; }
__device__ __forceinline__ void storev(u16* p, int i, float v)   { p[i] = f2bf(v); }
__device__ __forceinline__ float rawf(float x) { return x; }
__device__ __forceinline__ float rawf(u16 x)   { return bf2f(x); }

struct Coords { int idx; float fx, fy, fz; };

__device__ __forceinline__ Coords coords_for(float px, float py, float pz) {
    float gx = fminf(fmaxf((px + 1.0f) * 79.5f, 0.0f), 159.0f);
    float gy = fminf(fmaxf((py + 1.0f) * 79.5f, 0.0f), 159.0f);
    float gz = fminf(fmaxf((pz + 1.0f) * 79.5f, 0.0f), 159.0f);
    int ix = (int)gx; if (ix > 158) ix = 158;
    int iy = (int)gy; if (iy > 158) iy = 158;
    int iz = (int)gz; if (iz > 158) iz = 158;
    Coords c;
    c.idx = (ix * G + iy) * G + iz;
    c.fx = gx - (float)ix; c.fy = gy - (float)iy; c.fz = gz - (float)iz;
    return c;
}

template <typename T>
__device__ __forceinline__ float trilerp(const T* __restrict__ g, Coords c) {
    float c000 = loadv(g, c.idx);
    float c001 = loadv(g, c.idx + 1);
    float c010 = loadv(g, c.idx + G);
    float c011 = loadv(g, c.idx + G + 1);
    float c100 = loadv(g, c.idx + G2);
    float c101 = loadv(g, c.idx + G2 + 1);
    float c110 = loadv(g, c.idx + G2 + G);
    float c111 = loadv(g, c.idx + G2 + G + 1);
    float c00 = c000 * (1.0f - c.fz) + c001 * c.fz;
    float c01 = c010 * (1.0f - c.fz) + c011 * c.fz;
    float c10 = c100 * (1.0f - c.fz) + c101 * c.fz;
    float c11 = c110 * (1.0f - c.fz) + c111 * c.fz;
    float c0 = c00 * (1.0f - c.fy) + c01 * c.fy;
    float c1 = c10 * (1.0f - c.fy) + c11 * c.fy;
    return c0 * (1.0f - c.fx) + c1 * c.fx;
}

// mode: 0 = buffers hold bf16, 1 = buffers hold fp32
__global__ void decide_mode(const u16* __restrict__ rays_d_u16, int* __restrict__ mode) {
    if (blockIdx.x == 0 && threadIdx.x == 0) {
        int bad = 0;
        for (int i = 0; i < 128; i++) {
            u16 u = rays_d_u16[i];
            int e = (u >> 7) & 0xFF;
            int m = u & 0x7F;
            float v = bf2f(u);
            if (e == 0xFF || (e == 0 && m != 0) || fabsf(v) > 32.0f) bad++;
        }
        *mode = (bad >= 4) ? 1 : 0;
    }
}

template <typename T, typename OT, int MODE>
__global__ __launch_bounds__(256, 3)
void dvgo_fused(const T* __restrict__ rays_o, const T* __restrict__ rays_d,
                const T* __restrict__ density, const T* __restrict__ k0,
                const T* __restrict__ W0, const T* __restrict__ b0,
                const T* __restrict__ W1, const T* __restrict__ b1,
                const T* __restrict__ W2, const T* __restrict__ b2,
                OT* __restrict__ out, const int* __restrict__ mode)
{
    if (*mode != MODE) return;   // uniform early-exit for the wrong-dtype instantiation

    __shared__ __align__(16) u16   W1f[WIDTH * WIDTH];     // 32768 B  swizzled B-frag layout
    __shared__ __align__(16) u16   h0B[CHUNK * HBS];       // 8704 B   h0 bf16 [sample][k]
    __shared__ __align__(16) u16   W0h[K0DIM * WIDTH];     // 3072 B
    __shared__ __align__(16) float featT[K0DIM * HSTR];    // 1728 B
    __shared__ __align__(16) float W2Tf[3 * WIDTH];        // 1536 B
    __shared__ float p2[CHUNK * 6];                        // 768 B  [s][nh][c]
    __shared__ float base0[WIDTH];
    __shared__ float b1s[WIDTH];
    __shared__ float b2s[3];
    __shared__ float vembs[27];
    __shared__ float wts[NS];
    __shared__ float red[96];
    __shared__ float ainvs;

    const int r = blockIdx.x;
    const int tid = threadIdx.x;

    const float o0 = loadv(rays_o, r*3+0);
    const float o1 = loadv(rays_o, r*3+1);
    const float o2 = loadv(rays_o, r*3+2);
    const float d0 = loadv(rays_d, r*3+0);
    const float d1 = loadv(rays_d, r*3+1);
    const float d2 = loadv(rays_d, r*3+2);

    // ---- stage weights into LDS ----
    for (int idx = tid; idx < WIDTH*WIDTH; idx += 256) {
        int k = idx >> 7, n = idx & 127;
        W1f[W1F_IDX(k >> 5, (k >> 3) & 3, n) + (k & 7)] = f2bf(loadv(W1, idx));
    }
    for (int k = tid; k < K0DIM*WIDTH; k += 256) W0h[k] = f2bf(loadv(W0, k));
    for (int k = tid; k < 3*WIDTH; k += 256) {
        int c = k >> 7, i = k & 127;
        W2Tf[k] = loadv(W2, i*3 + c);
    }
    if (tid < WIDTH) b1s[tid] = loadv(b1, tid);
    if (tid < 3)     b2s[tid] = loadv(b2, tid);

    // ---- view embedding (per-ray constant) ----
    if (tid < 27) {
        float inv = rsqrtf(d0*d0 + d1*d1 + d2*d2);
        float v0 = d0*inv, v1 = d1*inv, v2 = d2*inv;
        float val;
        if (tid < 3) {
            val = (tid == 0) ? v0 : ((tid == 1) ? v1 : v2);
        } else if (tid < 15) {
            int t2 = tid - 3; int dd = t2 >> 2; int p = t2 & 3;
            float vd = (dd == 0) ? v0 : ((dd == 1) ? v1 : v2);
            val = sinf(vd * (float)(1 << p));
        } else {
            int t2 = tid - 15; int dd = t2 >> 2; int p = t2 & 3;
            float vd = (dd == 0) ? v0 : ((dd == 1) ? v1 : v2);
            val = cosf(vd * (float)(1 << p));
        }
        vembs[tid] = val;
    }
    __syncthreads();

    // ---- base0 = b0 + vemb @ W0[12:39]  (per-ray) ----
    if (tid < WIDTH) {
        float a = loadv(b0, tid);
        #pragma unroll
        for (int i = 0; i < 27; i++)
            a += vembs[i] * loadv(W0, (K0DIM + i)*WIDTH + tid);
        base0[tid] = a;
    }

    // ---- alpha for my sample ----
    {
        int s = tid;
        float tv = TNEAR + (TFAR - TNEAR) * ((float)s * (1.0f/(float)(NS-1)));
        Coords c = coords_for(o0 + d0*tv, o1 + d1*tv, o2 + d2*tv);
        float sigma = trilerp(density, c);
        float alpha = 1.0f - rsqrtf(1.0f + __expf(sigma + ACT_SHIFT_F));
        wts[s] = alpha;
    }
    __syncthreads();

    // ---- serial transmittance scan ----
    if (tid == 0) {
        float w = 1.0f;
        for (int s = 0; s < NS; s++) {
            float a = wts[s];
            wts[s] = a * w;
            w *= (1.0f - a + 1e-10f);
        }
        ainvs = w;
    }
    __syncthreads();

    // ---- per-thread role constants ----
    const int jt = tid & 31;
    const int st = tid >> 5;
    const int j0 = jt * 4;
    const int s0 = st * 4;

    const int lane = tid & 63;
    const int wvid = tid >> 6;
    const int mt   = wvid & 1;
    const int nh   = wvid >> 1;
    const int q    = lane >> 4;
    const int ncol = lane & 15;
    const int arow = mt*16 + ncol;
    const int kcol = q * 8;
    const int drow0 = mt*16 + q*4;

    // gather-prefetch state (2 tasks: tid and tid+256 if < 384)
    T    raw0[8], raw1[8];
    float fr0[3], fr1[3];
    const int ch0 = tid >> 5;              // task 0 channel (0..7)
    const int sl0 = tid & 31;
    const int ch1 = 8 + (tid >> 5);        // task 1 channel (8..11) for tid<128
    const int sl1 = tid & 31;
    const bool has1 = (tid < 128);

    #define ISSUE_GATHER(CH, SL, C0N, RAW, FR)                                  \
        { int s_ = (C0N) + (SL);                                                \
          float tv_ = TNEAR + (TFAR - TNEAR) * ((float)s_ * (1.0f/255.0f));     \
          Coords c_ = coords_for(o0 + d0*tv_, o1 + d1*tv_, o2 + d2*tv_);        \
          const T* g_ = k0 + (size_t)(CH)*G3;                                   \
          RAW[0] = g_[c_.idx];          RAW[1] = g_[c_.idx + 1];                \
          RAW[2] = g_[c_.idx + G];      RAW[3] = g_[c_.idx + G + 1];            \
          RAW[4] = g_[c_.idx + G2];     RAW[5] = g_[c_.idx + G2 + 1];           \
          RAW[6] = g_[c_.idx + G2 + G]; RAW[7] = g_[c_.idx + G2 + G + 1];       \
          FR[0] = c_.fx; FR[1] = c_.fy; FR[2] = c_.fz; }

    #define COMMIT_GATHER(CH, SL, RAW, FR)                                      \
        { float fz_ = FR[2], fy_ = FR[1], fx_ = FR[0];                          \
          float c00_ = rawf(RAW[0])*(1.0f-fz_) + rawf(RAW[1])*fz_;              \
          float c01_ = rawf(RAW[2])*(1.0f-fz_) + rawf(RAW[3])*fz_;              \
          float c10_ = rawf(RAW[4])*(1.0f-fz_) + rawf(RAW[5])*fz_;              \
          float c11_ = rawf(RAW[6])*(1.0f-fz_) + rawf(RAW[7])*fz_;              \
          float c0_ = c00_*(1.0f-fy_) + c01_*fy_;                               \
          float c1_ = c10_*(1.0f-fy_) + c11_*fy_;                               \
          featT[(CH)*HSTR + (SL)] = c0_*(1.0f-fx_) + c1_*fx_; }

    // prologue: gather chunk 0
    ISSUE_GATHER(ch0, sl0, 0, raw0, fr0);
    if (has1) ISSUE_GATHER(ch1, sl1, 0, raw1, fr1);

    float rgbacc = 0.0f;

    for (int cc = 0; cc < NCHUNK; cc++) {
        const int c0 = cc * CHUNK;

        // (a) commit gathered corners -> featT
        COMMIT_GATHER(ch0, sl0, raw0, fr0);
        if (has1) COMMIT_GATHER(ch1, sl1, raw1, fr1);
        __syncthreads();   // A: featT ready

        // (b) layer 0: h0 = relu(base0 + feat @ W0[0:12]) -> bf16 LDS [sample][k]
        {
            float acc[4][4];
            #pragma unroll
            for (int rr = 0; rr < 4; rr++) {
                float v = base0[j0+rr];
                acc[rr][0] = v; acc[rr][1] = v; acc[rr][2] = v; acc[rr][3] = v;
            }
            #pragma unroll
            for (int i = 0; i < K0DIM; i++) {
                float4 xv = *(const float4*)&featT[i*HSTR + s0];
                ushort4 wv = *(const ushort4*)&W0h[i*WIDTH + j0];
                float w;
                w = bf2f(wv.x); acc[0][0]+=w*xv.x; acc[0][1]+=w*xv.y; acc[0][2]+=w*xv.z; acc[0][3]+=w*xv.w;
                w = bf2f(wv.y); acc[1][0]+=w*xv.x; acc[1][1]+=w*xv.y; acc[1][2]+=w*xv.z; acc[1][3]+=w*xv.w;
                w = bf2f(wv.z); acc[2][0]+=w*xv.x; acc[2][1]+=w*xv.y; acc[2][2]+=w*xv.z; acc[2][3]+=w*xv.w;
                w = bf2f(wv.w); acc[3][0]+=w*xv.x; acc[3][1]+=w*xv.y; acc[3][2]+=w*xv.z; acc[3][3]+=w*xv.w;
            }
            #pragma unroll
            for (int si = 0; si < 4; si++) {
                ushort4 h;
                h.x = f2bf(fmaxf(acc[0][si], 0.0f));
                h.y = f2bf(fmaxf(acc[1][si], 0.0f));
                h.z = f2bf(fmaxf(acc[2][si], 0.0f));
                h.w = f2bf(fmaxf(acc[3][si], 0.0f));
                *(ushort4*)&h0B[(s0+si)*HBS + j0] = h;
            }
        }
        __syncthreads();   // B: h0B ready

        // (c) issue next chunk's gathers (overlaps MFMA), then MFMA layer 1
        if (cc + 1 < NCHUNK) {
            ISSUE_GATHER(ch0, sl0, c0 + CHUNK, raw0, fr0);
            if (has1) ISSUE_GATHER(ch1, sl1, c0 + CHUNK, raw1, fr1);
        }

        {
            floatx4 acc[4];
            #pragma unroll
            for (int t = 0; t < 4; t++) {
                float bj = b1s[nh*64 + t*16 + ncol];
                acc[t] = (floatx4){bj, bj, bj, bj};
            }
            #pragma unroll
            for (int kq = 0; kq < 4; kq++) {
                short8 af = *(const short8*)&h0B[arow*HBS + kq*32 + kcol];
                #pragma unroll
                for (int t = 0; t < 4; t++) {
                    short8 bf = *(const short8*)&W1f[W1F_IDX(kq, q, nh*64 + t*16 + ncol)];
                    acc[t] = __builtin_amdgcn_mfma_f32_16x16x32_bf16(af, bf, acc[t], 0, 0, 0);
                }
            }

            // fused layer 2: per-lane partials over the 4 cols this lane owns
            float p[3][4];
            #pragma unroll
            for (int c = 0; c < 3; c++)
                { p[c][0]=0; p[c][1]=0; p[c][2]=0; p[c][3]=0; }
            #pragma unroll
            for (int t = 0; t < 4; t++) {
                int j = nh*64 + t*16 + ncol;
                float w20 = W2Tf[j], w21 = W2Tf[WIDTH + j], w22 = W2Tf[2*WIDTH + j];
                #pragma unroll
                for (int rI = 0; rI < 4; rI++) {
                    float h = fmaxf(acc[t][rI], 0.0f);
                    p[0][rI] += h * w20;
                    p[1][rI] += h * w21;
                    p[2][rI] += h * w22;
                }
            }
            // reduce over the 16 ncol lanes (bits 0..3 of lane)
            #pragma unroll
            for (int m = 1; m <= 8; m <<= 1) {
                #pragma unroll
                for (int c = 0; c < 3; c++) {
                    #pragma unroll
                    for (int rI = 0; rI < 4; rI++)
                        p[c][rI] += __shfl_xor(p[c][rI], m, 64);
                }
            }
            if (ncol == 0) {
                #pragma unroll
                for (int rI = 0; rI < 4; rI++) {
                    #pragma unroll
                    for (int c = 0; c < 3; c++)
                        p2[(drow0 + rI)*6 + nh*3 + c] = p[c][rI];
                }
            }
        }
        __syncthreads();   // C: p2 ready (also h0B consumed before next (b))

        // (d) sigmoid + weighted accumulate (96 threads)
        if (tid < 96) {
            int c = tid >> 5, s = tid & 31;
            float acc2 = b2s[c] + p2[s*6 + c] + p2[s*6 + 3 + c];
            float rgb = 1.0f / (1.0f + __expf(-acc2));
            rgbacc += wts[c0 + s] * rgb;
        }
        // no barrier needed: next p2 write is after next barrier B
    }

    if (tid < 96) red[tid] = rgbacc;
    __syncthreads();
    if (tid < 3) {
        float s = 0.0f;
        #pragma unroll
        for (int k = 0; k < 32; k++) s += red[tid*32 + k];
        storev(out, r*3 + tid, s + ainvs);
    }
    #undef ISSUE_GATHER
    #undef COMMIT_GATHER
}

extern "C" void kernel_launch(void* const* d_in, const int* in_sizes, int n_in,
                              void* d_out, int out_size, void* d_ws, size_t ws_size,
                              hipStream_t stream) {
    int* mode = (int*)d_ws;
    decide_mode<<<dim3(1), dim3(64), 0, stream>>>((const u16*)d_in[1], mode);

    // bf16 interpretation
    dvgo_fused<u16, u16, 0><<<dim3(NRAYS), dim3(256), 0, stream>>>(
        (const u16*)d_in[0], (const u16*)d_in[1], (const u16*)d_in[2],
        (const u16*)d_in[3], (const u16*)d_in[4], (const u16*)d_in[5],
        (const u16*)d_in[6], (const u16*)d_in[7], (const u16*)d_in[8],
        (const u16*)d_in[9], (u16*)d_out, mode);

    // fp32 interpretation
    dvgo_fused<float, float, 1><<<dim3(NRAYS), dim3(256), 0, stream>>>(
        (const float*)d_in[0], (const float*)d_in[1], (const float*)d_in[2],
        (const float*)d_in[3], (const float*)d_in[4], (const float*)d_in[5],
        (const float*)d_in[6], (const float*)d_in[7], (const float*)d_in[8],
        (const float*)d_in[9], (float*)d_out, mode);
}

// Round 5
// 522.304 us; speedup vs baseline: 1.8435x; 1.0443x over previous
//
#include <hip/hip_runtime.h>
#include <hip/hip_bf16.h>

#define NRAYS 4096
#define NS 256
#define G 160
#define G2 (160*160)
#define G3 (160*160*160)
#define K0DIM 12
#define WIDTH 128
#define CHUNK 32
#define NCHUNK 8
#define HBS 136              // h0B bf16 row stride (272 B: 16B-aligned rows, 2-way banks = free)
#define ACT_SHIFT_F (-4.5951198501345889f)
#define TNEAR 0.2f
#define TFAR 1.8f

typedef unsigned short u16;
typedef unsigned int u32;
typedef __attribute__((ext_vector_type(8))) short short8;   // 8 bf16 = 4 VGPRs (MFMA A/B frag)
typedef __attribute__((ext_vector_type(4))) float floatx4;  // MFMA C/D frag

// W1f[kq][qsub][col][j]: B-frag for (kq, quarter qsub, output col) = 16 contiguous bytes
#define W1F_IDX(kq, qs, n) (((((kq)<<2) + (qs)) * 128 + (n)) << 3)

__device__ __forceinline__ float bf2f(u16 u) {
    union { u32 i; float f; } v; v.i = ((u32)u) << 16; return v.f;
}
__device__ __forceinline__ u16 f2bf(float f) {   // RTNE fp32 -> bf16
    union { float f; u32 u; } v; v.f = f;
    u32 r = v.u + 0x7FFFu + ((v.u >> 16) & 1u);
    return (u16)(r >> 16);
}

__device__ __forceinline__ float loadv(const float* p, int i) { return p[i]; }
__device__ __forceinline__ float loadv(const u16* p, int i)   { return bf2f(p[i]); }
__device__ __forceinline__ void storev(float* p, int i, float v) { p[i] = v; }
__device__ __forceinline__ void storev(u16* p, int i, float v)   { p[i] = f2bf(v); }

// z-quad raw vector type per dtype
template <typename T> struct QT;
template <> struct QT<u16>   { using type = ushort4; };
template <> struct QT<float> { using type = float4;  };

// select values at (z0, z0+1) = quad[d], quad[d+1], d in {0,1,2}
__device__ __forceinline__ void zpair(const ushort4& q, int d, float& v0, float& v1) {
    u16 r0 = (d == 0) ? q.x : ((d == 1) ? q.y : q.z);
    u16 r1 = (d == 0) ? q.y : ((d == 1) ? q.z : q.w);
    v0 = bf2f(r0); v1 = bf2f(r1);
}
__device__ __forceinline__ void zpair(const float4& q, int d, float& v0, float& v1) {
    v0 = (d == 0) ? q.x : ((d == 1) ? q.y : q.z);
    v1 = (d == 0) ? q.y : ((d == 1) ? q.z : q.w);
}

struct CoordsE { int base; int d; float fx, fy, fz; };

__device__ __forceinline__ CoordsE coords_e(float px, float py, float pz) {
    float gx = fminf(fmaxf((px + 1.0f) * 79.5f, 0.0f), 159.0f);
    float gy = fminf(fmaxf((py + 1.0f) * 79.5f, 0.0f), 159.0f);
    float gz = fminf(fmaxf((pz + 1.0f) * 79.5f, 0.0f), 159.0f);
    int ix = (int)gx; if (ix > 158) ix = 158;
    int iy = (int)gy; if (iy > 158) iy = 158;
    int iz = (int)gz; if (iz > 158) iz = 158;
    int ze = iz & ~1; if (ze > 156) ze = 156;
    CoordsE c;
    c.base = (ix * G + iy) * G + ze;
    c.d = iz - ze;
    c.fx = gx - (float)ix; c.fy = gy - (float)iy; c.fz = gz - (float)iz;
    return c;
}

// mode: 0 = buffers hold bf16, 1 = buffers hold fp32
__global__ void decide_mode(const u16* __restrict__ rays_d_u16, int* __restrict__ mode) {
    if (blockIdx.x == 0 && threadIdx.x == 0) {
        int bad = 0;
        for (int i = 0; i < 128; i++) {
            u16 u = rays_d_u16[i];
            int e = (u >> 7) & 0xFF;
            int m = u & 0x7F;
            float v = bf2f(u);
            if (e == 0xFF || (e == 0 && m != 0) || fabsf(v) > 32.0f) bad++;
        }
        *mode = (bad >= 4) ? 1 : 0;
    }
}

template <typename T, typename OT, int MODE>
__global__ __launch_bounds__(256, 3)
void dvgo_fused(const T* __restrict__ rays_o, const T* __restrict__ rays_d,
                const T* __restrict__ density, const T* __restrict__ k0,
                const T* __restrict__ W0, const T* __restrict__ b0,
                const T* __restrict__ W1, const T* __restrict__ b1,
                const T* __restrict__ W2, const T* __restrict__ b2,
                OT* __restrict__ out, const int* __restrict__ mode)
{
    if (*mode != MODE) return;   // uniform early-exit for the wrong-dtype instantiation

    using qvec = typename QT<T>::type;

    __shared__ __align__(16) u16   W1f[WIDTH * WIDTH];     // 32768 B  swizzled B-frag layout
    __shared__ __align__(16) u16   h0B[CHUNK * HBS];       // 8704 B   h0 bf16 [sample][k]
    __shared__ __align__(16) u16   W0f[WIDTH * 16];        // 4096 B   W0T[n][k], k 12..15 = 0
    __shared__ __align__(16) u16   featB[CHUNK * 16];      // 1024 B   feat bf16 [sample][k<=15]
    __shared__ __align__(16) float W2Tf[3 * WIDTH];        // 1536 B
    __shared__ float p2[CHUNK * 6];                        // 768 B  [s][nh][c]
    __shared__ float base0[WIDTH];
    __shared__ float b1s[WIDTH];
    __shared__ float b2s[3];
    __shared__ float vembs[27];
    __shared__ float wts[NS];
    __shared__ float red[96];
    __shared__ float ainvs;

    const int r = blockIdx.x;
    const int tid = threadIdx.x;

    const float o0 = loadv(rays_o, r*3+0);
    const float o1 = loadv(rays_o, r*3+1);
    const float o2 = loadv(rays_o, r*3+2);
    const float d0 = loadv(rays_d, r*3+0);
    const float d1 = loadv(rays_d, r*3+1);
    const float d2 = loadv(rays_d, r*3+2);

    // ---- stage weights into LDS ----
    for (int idx = tid; idx < WIDTH*WIDTH; idx += 256) {
        int k = idx >> 7, n = idx & 127;
        W1f[W1F_IDX(k >> 5, (k >> 3) & 3, n) + (k & 7)] = f2bf(loadv(W1, idx));
    }
    for (int i = tid; i < WIDTH*16; i += 256) {
        int n = i >> 4, k = i & 15;
        W0f[i] = (k < K0DIM) ? f2bf(loadv(W0, k*WIDTH + n)) : (u16)0;
    }
    for (int i = tid; i < CHUNK*4; i += 256)          // featB k=12..15 stays 0 forever
        featB[(i >> 2)*16 + 12 + (i & 3)] = 0;
    for (int k = tid; k < 3*WIDTH; k += 256) {
        int c = k >> 7, i = k & 127;
        W2Tf[k] = loadv(W2, i*3 + c);
    }
    if (tid < WIDTH) b1s[tid] = loadv(b1, tid);
    if (tid < 3)     b2s[tid] = loadv(b2, tid);

    // ---- view embedding (per-ray constant) ----
    if (tid < 27) {
        float inv = rsqrtf(d0*d0 + d1*d1 + d2*d2);
        float v0 = d0*inv, v1 = d1*inv, v2 = d2*inv;
        float val;
        if (tid < 3) {
            val = (tid == 0) ? v0 : ((tid == 1) ? v1 : v2);
        } else if (tid < 15) {
            int t2 = tid - 3; int dd = t2 >> 2; int p = t2 & 3;
            float vd = (dd == 0) ? v0 : ((dd == 1) ? v1 : v2);
            val = sinf(vd * (float)(1 << p));
        } else {
            int t2 = tid - 15; int dd = t2 >> 2; int p = t2 & 3;
            float vd = (dd == 0) ? v0 : ((dd == 1) ? v1 : v2);
            val = cosf(vd * (float)(1 << p));
        }
        vembs[tid] = val;
    }
    __syncthreads();

    // ---- base0 = b0 + vemb @ W0[12:39]  (per-ray) ----
    if (tid < WIDTH) {
        float a = loadv(b0, tid);
        #pragma unroll
        for (int i = 0; i < 27; i++)
            a += vembs[i] * loadv(W0, (K0DIM + i)*WIDTH + tid);
        base0[tid] = a;
    }

    // ---- alpha for my sample (quad-load gather) ----
    {
        int s = tid;
        float tv = TNEAR + (TFAR - TNEAR) * ((float)s * (1.0f/(float)(NS-1)));
        CoordsE c = coords_e(o0 + d0*tv, o1 + d1*tv, o2 + d2*tv);
        qvec q00 = *(const qvec*)(density + c.base);
        qvec q01 = *(const qvec*)(density + c.base + G);
        qvec q10 = *(const qvec*)(density + c.base + G2);
        qvec q11 = *(const qvec*)(density + c.base + G2 + G);
        float a0,a1,b0v,b1v,c0v,c1v,d0v,d1v;
        zpair(q00, c.d, a0, a1); zpair(q01, c.d, b0v, b1v);
        zpair(q10, c.d, c0v, c1v); zpair(q11, c.d, d0v, d1v);
        float c00 = a0*(1.0f-c.fz) + a1*c.fz;
        float c01 = b0v*(1.0f-c.fz) + b1v*c.fz;
        float c10 = c0v*(1.0f-c.fz) + c1v*c.fz;
        float c11 = d0v*(1.0f-c.fz) + d1v*c.fz;
        float e0 = c00*(1.0f-c.fy) + c01*c.fy;
        float e1 = c10*(1.0f-c.fy) + c11*c.fy;
        float sigma = e0*(1.0f-c.fx) + e1*c.fx;
        float alpha = 1.0f - rsqrtf(1.0f + __expf(sigma + ACT_SHIFT_F));
        wts[s] = alpha;
    }
    __syncthreads();

    // ---- serial transmittance scan ----
    if (tid == 0) {
        float w = 1.0f;
        for (int s = 0; s < NS; s++) {
            float a = wts[s];
            wts[s] = a * w;
            w *= (1.0f - a + 1e-10f);
        }
        ainvs = w;
    }
    __syncthreads();

    // ---- per-thread role constants ----
    const int lane = tid & 63;
    const int wvid = tid >> 6;
    const int mt   = wvid & 1;
    const int nh   = wvid >> 1;
    const int q    = lane >> 4;
    const int ncol = lane & 15;
    const int arow = mt*16 + ncol;
    const int kcol = q * 8;
    const int drow0 = mt*16 + q*4;

    // gather-prefetch state (2 tasks: tid and tid+256 if < 384)
    qvec qa[4], qb[4];
    CoordsE cea, ceb;
    const int ch0 = tid >> 5;              // task 0 channel (0..7)
    const int sl0 = tid & 31;
    const int ch1 = 8 + (tid >> 5);        // task 1 channel (8..11) for tid<128
    const int sl1 = tid & 31;
    const bool has1 = (tid < 128);

    #define ISSUE_GATHER(CH, SL, C0N, Q, CE)                                    \
        { int s_ = (C0N) + (SL);                                                \
          float tv_ = TNEAR + (TFAR - TNEAR) * ((float)s_ * (1.0f/255.0f));     \
          CE = coords_e(o0 + d0*tv_, o1 + d1*tv_, o2 + d2*tv_);                 \
          const T* g_ = k0 + (size_t)(CH)*G3;                                   \
          Q[0] = *(const qvec*)(g_ + CE.base);                                  \
          Q[1] = *(const qvec*)(g_ + CE.base + G);                              \
          Q[2] = *(const qvec*)(g_ + CE.base + G2);                             \
          Q[3] = *(const qvec*)(g_ + CE.base + G2 + G); }

    #define COMMIT_GATHER(CH, SL, Q, CE)                                        \
        { float a0_,a1_,b0_,b1_,c0_,c1_,d0_,d1_;                                \
          zpair(Q[0], CE.d, a0_, a1_); zpair(Q[1], CE.d, b0_, b1_);             \
          zpair(Q[2], CE.d, c0_, c1_); zpair(Q[3], CE.d, d0_, d1_);             \
          float fz_ = CE.fz, fy_ = CE.fy, fx_ = CE.fx;                          \
          float c00_ = a0_*(1.0f-fz_) + a1_*fz_;                                \
          float c01_ = b0_*(1.0f-fz_) + b1_*fz_;                                \
          float c10_ = c0_*(1.0f-fz_) + c1_*fz_;                                \
          float c11_ = d0_*(1.0f-fz_) + d1_*fz_;                                \
          float e0_ = c00_*(1.0f-fy_) + c01_*fy_;                               \
          float e1_ = c10_*(1.0f-fy_) + c11_*fy_;                               \
          featB[(SL)*16 + (CH)] = f2bf(e0_*(1.0f-fx_) + e1_*fx_); }

    // prologue: gather chunk 0
    ISSUE_GATHER(ch0, sl0, 0, qa, cea);
    if (has1) ISSUE_GATHER(ch1, sl1, 0, qb, ceb);

    float rgbacc = 0.0f;

    for (int cc = 0; cc < NCHUNK; cc++) {
        const int c0 = cc * CHUNK;

        // (a) commit gathered corners -> featB (bf16)
        COMMIT_GATHER(ch0, sl0, qa, cea);
        if (has1) COMMIT_GATHER(ch1, sl1, qb, ceb);
        __syncthreads();   // A: featB ready

        // (b) layer 0 via MFMA (K=12 zero-padded to 32):
        //     h0[32][128] = relu(base0 + feat[32][12] @ W0[12][128])
        {
            short8 af0 = {};
            short8 bf0 = {}, bf1 = {}, bf2v = {}, bf3 = {};
            if (q < 2) {
                af0  = *(const short8*)&featB[arow*16 + kcol];
                bf0  = *(const short8*)&W0f[(nh*64 +  0 + ncol)*16 + kcol];
                bf1  = *(const short8*)&W0f[(nh*64 + 16 + ncol)*16 + kcol];
                bf2v = *(const short8*)&W0f[(nh*64 + 32 + ncol)*16 + kcol];
                bf3  = *(const short8*)&W0f[(nh*64 + 48 + ncol)*16 + kcol];
            }
            floatx4 acc0[4];
            #pragma unroll
            for (int t = 0; t < 4; t++) {
                float v = base0[nh*64 + t*16 + ncol];
                acc0[t] = (floatx4){v, v, v, v};
            }
            acc0[0] = __builtin_amdgcn_mfma_f32_16x16x32_bf16(af0, bf0,  acc0[0], 0, 0, 0);
            acc0[1] = __builtin_amdgcn_mfma_f32_16x16x32_bf16(af0, bf1,  acc0[1], 0, 0, 0);
            acc0[2] = __builtin_amdgcn_mfma_f32_16x16x32_bf16(af0, bf2v, acc0[2], 0, 0, 0);
            acc0[3] = __builtin_amdgcn_mfma_f32_16x16x32_bf16(af0, bf3,  acc0[3], 0, 0, 0);
            // epilogue: ReLU -> bf16 -> h0B[sample][k] (A-layout for layer 1)
            #pragma unroll
            for (int t = 0; t < 4; t++) {
                int j = nh*64 + t*16 + ncol;
                #pragma unroll
                for (int rI = 0; rI < 4; rI++)
                    h0B[(drow0 + rI)*HBS + j] = f2bf(fmaxf(acc0[t][rI], 0.0f));
            }
        }
        __syncthreads();   // B: h0B ready

        // (c) issue next chunk's gathers (overlaps MFMA), then MFMA layer 1 + fused layer 2
        if (cc + 1 < NCHUNK) {
            ISSUE_GATHER(ch0, sl0, c0 + CHUNK, qa, cea);
            if (has1) ISSUE_GATHER(ch1, sl1, c0 + CHUNK, qb, ceb);
        }

        {
            floatx4 acc[4];
            #pragma unroll
            for (int t = 0; t < 4; t++) {
                float bj = b1s[nh*64 + t*16 + ncol];
                acc[t] = (floatx4){bj, bj, bj, bj};
            }
            #pragma unroll
            for (int kq = 0; kq < 4; kq++) {
                short8 af = *(const short8*)&h0B[arow*HBS + kq*32 + kcol];
                #pragma unroll
                for (int t = 0; t < 4; t++) {
                    short8 bf = *(const short8*)&W1f[W1F_IDX(kq, q, nh*64 + t*16 + ncol)];
                    acc[t] = __builtin_amdgcn_mfma_f32_16x16x32_bf16(af, bf, acc[t], 0, 0, 0);
                }
            }

            // fused layer 2: per-lane partials over the 4 cols this lane owns
            float p[3][4];
            #pragma unroll
            for (int c = 0; c < 3; c++)
                { p[c][0]=0; p[c][1]=0; p[c][2]=0; p[c][3]=0; }
            #pragma unroll
            for (int t = 0; t < 4; t++) {
                int j = nh*64 + t*16 + ncol;
                float w20 = W2Tf[j], w21 = W2Tf[WIDTH + j], w22 = W2Tf[2*WIDTH + j];
                #pragma unroll
                for (int rI = 0; rI < 4; rI++) {
                    float h = fmaxf(acc[t][rI], 0.0f);
                    p[0][rI] += h * w20;
                    p[1][rI] += h * w21;
                    p[2][rI] += h * w22;
                }
            }
            // reduce over the 16 ncol lanes (bits 0..3 of lane)
            #pragma unroll
            for (int m = 1; m <= 8; m <<= 1) {
                #pragma unroll
                for (int c = 0; c < 3; c++) {
                    #pragma unroll
                    for (int rI = 0; rI < 4; rI++)
                        p[c][rI] += __shfl_xor(p[c][rI], m, 64);
                }
            }
            if (ncol == 0) {
                #pragma unroll
                for (int rI = 0; rI < 4; rI++) {
                    #pragma unroll
                    for (int c = 0; c < 3; c++)
                        p2[(drow0 + rI)*6 + nh*3 + c] = p[c][rI];
                }
            }
        }
        __syncthreads();   // C: p2 ready (also h0B consumed before next (b))

        // (d) sigmoid + weighted accumulate (96 threads)
        if (tid < 96) {
            int c = tid >> 5, s = tid & 31;
            float acc2 = b2s[c] + p2[s*6 + c] + p2[s*6 + 3 + c];
            float rgb = 1.0f / (1.0f + __expf(-acc2));
            rgbacc += wts[c0 + s] * rgb;
        }
        // no barrier needed: next p2 write is after next barriers A and B
    }

    if (tid < 96) red[tid] = rgbacc;
    __syncthreads();
    if (tid < 3) {
        float s = 0.0f;
        #pragma unroll
        for (int k = 0; k < 32; k++) s += red[tid*32 + k];
        storev(out, r*3 + tid, s + ainvs);
    }
    #undef ISSUE_GATHER
    #undef COMMIT_GATHER
}

extern "C" void kernel_launch(void* const* d_in, const int* in_sizes, int n_in,
                              void* d_out, int out_size, void* d_ws, size_t ws_size,
                              hipStream_t stream) {
    int* mode = (int*)d_ws;
    decide_mode<<<dim3(1), dim3(64), 0, stream>>>((const u16*)d_in[1], mode);

    // bf16 interpretation
    dvgo_fused<u16, u16, 0><<<dim3(NRAYS), dim3(256), 0, stream>>>(
        (const u16*)d_in[0], (const u16*)d_in[1], (const u16*)d_in[2],
        (const u16*)d_in[3], (const u16*)d_in[4], (const u16*)d_in[5],
        (const u16*)d_in[6], (const u16*)d_in[7], (const u16*)d_in[8],
        (const u16*)d_in[9], (u16*)d_out, mode);

    // fp32 interpretation
    dvgo_fused<float, float, 1><<<dim3(NRAYS), dim3(256), 0, stream>>>(
        (const float*)d_in[0], (const float*)d_in[1], (const float*)d_in[2],
        (const float*)d_in[3], (const float*)d_in[4], (const float*)d_in[5],
        (const float*)d_in[6], (const float*)d_in[7], (const float*)d_in[8],
        (const float*)d_in[9], (float*)d_out, mode);
}